// Round 1
// baseline (1086.162 us; speedup 1.0000x reference)
//
#include <hip/hip_runtime.h>

#define NU 100000      // users
#define NI 50000       // items
#define NN 150000      // total nodes
#define DIM 128        // embedding dim
#define NE 2000000     // directed edges (symmetrized)

// ---------------- CSR build ----------------

__global__ void zero_kernel(int* __restrict__ p, int n) {
    int i = blockIdx.x * blockDim.x + threadIdx.x;
    if (i < n) p[i] = 0;
}

__global__ void hist_kernel(const int* __restrict__ col, int* __restrict__ deg) {
    int e = blockIdx.x * blockDim.x + threadIdx.x;
    if (e < NE) atomicAdd(&deg[col[e]], 1);
}

__global__ void dinv_kernel(const int* __restrict__ deg, float* __restrict__ dinv) {
    int i = blockIdx.x * blockDim.x + threadIdx.x;
    if (i < NN) {
        int d = deg[i];
        // reference: where(deg>0, rsqrt(max(deg,1)), 0); deg is an exact count
        dinv[i] = (d > 0) ? 1.0f / sqrtf((float)d) : 0.0f;
    }
}

// exclusive scan of deg[0..NN) -> ptr[0..NN], single block of 1024 threads
__global__ __launch_bounds__(1024) void scan_kernel(const int* __restrict__ deg,
                                                    int* __restrict__ ptr) {
    __shared__ int sums[1024];
    const int C = (NN + 1023) / 1024;   // 147 elements per thread
    int t = threadIdx.x;
    int lo = t * C;
    int hi = min(lo + C, NN);
    int s = 0;
    for (int i = lo; i < hi; ++i) s += deg[i];
    sums[t] = s;
    __syncthreads();
    // Hillis-Steele inclusive scan over the 1024 partials
    for (int d = 1; d < 1024; d <<= 1) {
        int v = (t >= d) ? sums[t - d] : 0;
        __syncthreads();
        sums[t] += v;
        __syncthreads();
    }
    int off = (t == 0) ? 0 : sums[t - 1];
    for (int i = lo; i < hi; ++i) { ptr[i] = off; off += deg[i]; }
    if (t == 1023) ptr[NN] = sums[1023];   // == NE
}

__global__ void fill_kernel(const int* __restrict__ row, const int* __restrict__ col,
                            const int* __restrict__ ptr, int* __restrict__ fill,
                            int* __restrict__ adj) {
    int e = blockIdx.x * blockDim.x + threadIdx.x;
    if (e < NE) {
        int c = col[e];
        int p = atomicAdd(&fill[c], 1);
        adj[ptr[c] + p] = row[e];
    }
}

// ---------------- propagation ----------------
// One wave (64 lanes) per target node c; lane L holds dims [2L, 2L+1] (float2).
// Gather sources are split at NU: gA indexes rows [0,NU), gB rows [NU,NN).
// dout[c] = (prev[c] + dinv[c]*sum) * scale   (prev read from prevA/prevB split).
__global__ __launch_bounds__(256) void prop_kernel(
    const float* __restrict__ gA, const float* __restrict__ gB,
    const float* prevA, const float* prevB,            // may alias dout (L1/L2 RMW)
    const float* __restrict__ dinv, const int* __restrict__ ptr,
    const int* __restrict__ adj,
    float* __restrict__ xout, float* dout, float scale, int write_x)
{
    int wid = (blockIdx.x * blockDim.x + threadIdx.x) >> 6;
    if (wid >= NN) return;
    int lane = threadIdx.x & 63;
    int c = wid;
    int beg = ptr[c], end = ptr[c + 1];

    float ax = 0.f, ay = 0.f;
    int j = beg;
    // unroll-2: two independent gathers in flight
    for (; j + 2 <= end; j += 2) {
        int r0 = adj[j], r1 = adj[j + 1];
        float w0 = dinv[r0], w1 = dinv[r1];
        const float* s0 = (r0 < NU) ? gA + (size_t)r0 * DIM : gB + (size_t)(r0 - NU) * DIM;
        const float* s1 = (r1 < NU) ? gA + (size_t)r1 * DIM : gB + (size_t)(r1 - NU) * DIM;
        float2 v0 = *(const float2*)(s0 + lane * 2);
        float2 v1 = *(const float2*)(s1 + lane * 2);
        ax += w0 * v0.x + w1 * v1.x;
        ay += w0 * v0.y + w1 * v1.y;
    }
    if (j < end) {
        int r0 = adj[j];
        float w0 = dinv[r0];
        const float* s0 = (r0 < NU) ? gA + (size_t)r0 * DIM : gB + (size_t)(r0 - NU) * DIM;
        float2 v0 = *(const float2*)(s0 + lane * 2);
        ax += w0 * v0.x;
        ay += w0 * v0.y;
    }

    float dc = dinv[c];
    float nx = dc * ax, ny = dc * ay;

    if (write_x) {
        float2 o; o.x = nx; o.y = ny;
        *(float2*)(xout + (size_t)c * DIM + lane * 2) = o;
    }

    const float* pv = (c < NU) ? prevA + (size_t)c * DIM : prevB + (size_t)(c - NU) * DIM;
    float2 p = *(const float2*)(pv + lane * 2);
    float2 o2;
    o2.x = (p.x + nx) * scale;
    o2.y = (p.y + ny) * scale;
    *(float2*)(dout + (size_t)c * DIM + lane * 2) = o2;
}

// ---------------- launch ----------------

extern "C" void kernel_launch(void* const* d_in, const int* in_sizes, int n_in,
                              void* d_out, int out_size, void* d_ws, size_t ws_size,
                              hipStream_t stream) {
    const int* edge = (const int*)d_in[0];      // [2, NE] int32
    const int* row = edge;                      // sources
    const int* col = edge + NE;                 // targets
    const float* user = (const float*)d_in[1];  // [NU, DIM]
    const float* item = (const float*)d_in[2];  // [NI, DIM]
    float* out = (float*)d_out;                 // [NN, DIM] (users then items, contiguous)

    char* ws = (char*)d_ws;
    size_t off = 0;
    auto alloc = [&](size_t bytes) -> void* {
        void* p = ws + off;
        off = (off + bytes + 255) & ~(size_t)255;
        return p;
    };
    float* buf0 = (float*)alloc(sizeof(float) * (size_t)NN * DIM);  // 76.8 MB
    float* buf1 = (float*)alloc(sizeof(float) * (size_t)NN * DIM);  // 76.8 MB
    float* dinv = (float*)alloc(sizeof(float) * NN);
    int*   deg  = (int*)  alloc(sizeof(int) * 2 * NN);              // deg + fill contiguous
    int*   fill = deg + NN;
    int*   ptr  = (int*)  alloc(sizeof(int) * (NN + 1));
    int*   adj  = (int*)  alloc(sizeof(int) * NE);                  // 8 MB

    // CSR build (once per launch; ws is re-poisoned by the harness every call)
    zero_kernel<<<(2 * NN + 255) / 256, 256, 0, stream>>>(deg, 2 * NN);
    hist_kernel<<<(NE + 255) / 256, 256, 0, stream>>>(col, deg);
    dinv_kernel<<<(NN + 255) / 256, 256, 0, stream>>>(deg, dinv);
    scan_kernel<<<1, 1024, 0, stream>>>(deg, ptr);
    fill_kernel<<<(NE + 255) / 256, 256, 0, stream>>>(row, col, ptr, fill, adj);

    int blocks = (NN + 3) / 4;  // 4 waves (nodes) per 256-thread block
    // L0: gather from raw inputs; d_out = x0 + x1 (prev==x0 read from inputs)
    prop_kernel<<<blocks, 256, 0, stream>>>(user, item, user, item,
                                            dinv, ptr, adj, buf0, out, 1.0f, 1);
    // L1: gather from buf0; d_out += x2
    prop_kernel<<<blocks, 256, 0, stream>>>(buf0, buf0 + (size_t)NU * DIM,
                                            out, out + (size_t)NU * DIM,
                                            dinv, ptr, adj, buf1, out, 1.0f, 1);
    // L2: gather from buf1; d_out = (d_out + x3) * 0.25; skip dead x-write
    prop_kernel<<<blocks, 256, 0, stream>>>(buf1, buf1 + (size_t)NU * DIM,
                                            out, out + (size_t)NU * DIM,
                                            dinv, ptr, adj, buf0, out, 0.25f, 0);
}

// Round 2
// 827.752 us; speedup vs baseline: 1.3122x; 1.3122x over previous
//
#include <hip/hip_runtime.h>

#define NU 100000      // users
#define NI 50000       // items
#define NN 150000      // total nodes
#define DIM 128        // embedding dim
#define NE 2000000     // directed edges (symmetrized)

// ---------------- CSR build ----------------

__global__ void zero_kernel(int* __restrict__ p, int n) {
    int i = blockIdx.x * blockDim.x + threadIdx.x;
    if (i < n) p[i] = 0;
}

__global__ void hist_kernel(const int* __restrict__ col, int* __restrict__ deg) {
    int e = blockIdx.x * blockDim.x + threadIdx.x;
    if (e < NE) atomicAdd(&deg[col[e]], 1);
}

__global__ void dinv_kernel(const int* __restrict__ deg, float* __restrict__ dinv) {
    int i = blockIdx.x * blockDim.x + threadIdx.x;
    if (i < NN) {
        int d = deg[i];
        dinv[i] = (d > 0) ? 1.0f / sqrtf((float)d) : 0.0f;
    }
}

// Replace the serial exclusive scan with atomic segment allocation:
// wave-level shuffle prefix-scan over 64 degrees, ONE atomicAdd per wave.
// CSR segment order becomes nondeterministic, which is fine (fill is
// atomic-ordered anyway; prop uses end = ptr[c] + deg[c]).
__global__ void alloc_kernel(const int* __restrict__ deg, int* __restrict__ ptr,
                             int* __restrict__ counter) {
    int i = blockIdx.x * blockDim.x + threadIdx.x;
    int lane = threadIdx.x & 63;
    int d = (i < NN) ? deg[i] : 0;
    int incl = d;
    #pragma unroll
    for (int off = 1; off < 64; off <<= 1) {
        int v = __shfl_up(incl, off, 64);
        if (lane >= off) incl += v;
    }
    int total = __shfl(incl, 63, 64);
    int base = 0;
    if (lane == 63) base = atomicAdd(counter, total);
    base = __shfl(base, 63, 64);
    if (i < NN) ptr[i] = base + incl - d;   // exclusive within wave + wave base
}

__global__ void fill_kernel(const int* __restrict__ row, const int* __restrict__ col,
                            const int* __restrict__ ptr, int* __restrict__ fill,
                            int* __restrict__ adj) {
    int e = blockIdx.x * blockDim.x + threadIdx.x;
    if (e < NE) {
        int c = col[e];
        int p = atomicAdd(&fill[c], 1);
        adj[ptr[c] + p] = row[e];
    }
}

// ---------------- propagation ----------------
// One wave (64 lanes) per target node c; lane L holds dims [2L, 2L+1] (float2).
// Gather sources split at NU: gA rows [0,NU), gB rows [NU,NN).
// dout[c] = (prev[c] + dinv[c]*sum) * scale.
__global__ __launch_bounds__(256) void prop_kernel(
    const float* __restrict__ gA, const float* __restrict__ gB,
    const float* prevA, const float* prevB,            // may alias dout
    const float* __restrict__ dinv, const int* __restrict__ ptr,
    const int* __restrict__ deg, const int* __restrict__ adj,
    float* __restrict__ xout, float* dout, float scale, int write_x)
{
    int wid = (blockIdx.x * blockDim.x + threadIdx.x) >> 6;
    if (wid >= NN) return;
    int lane = threadIdx.x & 63;
    int c = wid;
    int beg = ptr[c];
    int end = beg + deg[c];

    float ax0 = 0.f, ay0 = 0.f, ax1 = 0.f, ay1 = 0.f;
    float ax2 = 0.f, ay2 = 0.f, ax3 = 0.f, ay3 = 0.f;
    int j = beg;
    // unroll-4: four independent 512B row-gathers in flight per wave
    for (; j + 4 <= end; j += 4) {
        int r0 = adj[j], r1 = adj[j + 1], r2 = adj[j + 2], r3 = adj[j + 3];
        float w0 = dinv[r0], w1 = dinv[r1], w2 = dinv[r2], w3 = dinv[r3];
        const float* s0 = (r0 < NU) ? gA + (size_t)r0 * DIM : gB + (size_t)(r0 - NU) * DIM;
        const float* s1 = (r1 < NU) ? gA + (size_t)r1 * DIM : gB + (size_t)(r1 - NU) * DIM;
        const float* s2 = (r2 < NU) ? gA + (size_t)r2 * DIM : gB + (size_t)(r2 - NU) * DIM;
        const float* s3 = (r3 < NU) ? gA + (size_t)r3 * DIM : gB + (size_t)(r3 - NU) * DIM;
        float2 v0 = *(const float2*)(s0 + lane * 2);
        float2 v1 = *(const float2*)(s1 + lane * 2);
        float2 v2 = *(const float2*)(s2 + lane * 2);
        float2 v3 = *(const float2*)(s3 + lane * 2);
        ax0 += w0 * v0.x; ay0 += w0 * v0.y;
        ax1 += w1 * v1.x; ay1 += w1 * v1.y;
        ax2 += w2 * v2.x; ay2 += w2 * v2.y;
        ax3 += w3 * v3.x; ay3 += w3 * v3.y;
    }
    for (; j < end; ++j) {
        int r0 = adj[j];
        float w0 = dinv[r0];
        const float* s0 = (r0 < NU) ? gA + (size_t)r0 * DIM : gB + (size_t)(r0 - NU) * DIM;
        float2 v0 = *(const float2*)(s0 + lane * 2);
        ax0 += w0 * v0.x; ay0 += w0 * v0.y;
    }
    float ax = (ax0 + ax1) + (ax2 + ax3);
    float ay = (ay0 + ay1) + (ay2 + ay3);

    float dc = dinv[c];
    float nx = dc * ax, ny = dc * ay;

    if (write_x) {
        float2 o; o.x = nx; o.y = ny;
        *(float2*)(xout + (size_t)c * DIM + lane * 2) = o;
    }

    const float* pv = (c < NU) ? prevA + (size_t)c * DIM : prevB + (size_t)(c - NU) * DIM;
    float2 p = *(const float2*)(pv + lane * 2);
    float2 o2;
    o2.x = (p.x + nx) * scale;
    o2.y = (p.y + ny) * scale;
    *(float2*)(dout + (size_t)c * DIM + lane * 2) = o2;
}

// ---------------- launch ----------------

extern "C" void kernel_launch(void* const* d_in, const int* in_sizes, int n_in,
                              void* d_out, int out_size, void* d_ws, size_t ws_size,
                              hipStream_t stream) {
    const int* edge = (const int*)d_in[0];      // [2, NE] int32
    const int* row = edge;                      // sources
    const int* col = edge + NE;                 // targets
    const float* user = (const float*)d_in[1];  // [NU, DIM]
    const float* item = (const float*)d_in[2];  // [NI, DIM]
    float* out = (float*)d_out;                 // [NN, DIM]

    char* ws = (char*)d_ws;
    size_t off = 0;
    auto alloc = [&](size_t bytes) -> void* {
        void* p = ws + off;
        off = (off + bytes + 255) & ~(size_t)255;
        return p;
    };
    float* buf0 = (float*)alloc(sizeof(float) * (size_t)NN * DIM);  // 76.8 MB
    float* buf1 = (float*)alloc(sizeof(float) * (size_t)NN * DIM);  // 76.8 MB
    float* dinv = (float*)alloc(sizeof(float) * NN);
    int*   deg  = (int*)  alloc(sizeof(int) * (2 * NN + 1));        // deg + fill + counter
    int*   fill = deg + NN;
    int*   cntr = deg + 2 * NN;
    int*   ptr  = (int*)  alloc(sizeof(int) * NN);
    int*   adj  = (int*)  alloc(sizeof(int) * NE);                  // 8 MB

    zero_kernel<<<(2 * NN + 1 + 255) / 256, 256, 0, stream>>>(deg, 2 * NN + 1);
    hist_kernel<<<(NE + 255) / 256, 256, 0, stream>>>(col, deg);
    dinv_kernel<<<(NN + 255) / 256, 256, 0, stream>>>(deg, dinv);
    alloc_kernel<<<(NN + 255) / 256, 256, 0, stream>>>(deg, ptr, cntr);
    fill_kernel<<<(NE + 255) / 256, 256, 0, stream>>>(row, col, ptr, fill, adj);

    int blocks = (NN + 3) / 4;  // 4 waves (nodes) per 256-thread block
    // L0: gather from raw inputs; d_out = x0 + x1
    prop_kernel<<<blocks, 256, 0, stream>>>(user, item, user, item,
                                            dinv, ptr, deg, adj, buf0, out, 1.0f, 1);
    // L1: gather from buf0; d_out += x2
    prop_kernel<<<blocks, 256, 0, stream>>>(buf0, buf0 + (size_t)NU * DIM,
                                            out, out + (size_t)NU * DIM,
                                            dinv, ptr, deg, adj, buf1, out, 1.0f, 1);
    // L2: gather from buf1; d_out = (d_out + x3) * 0.25; dead x-write skipped
    prop_kernel<<<blocks, 256, 0, stream>>>(buf1, buf1 + (size_t)NU * DIM,
                                            out, out + (size_t)NU * DIM,
                                            dinv, ptr, deg, adj, buf0, out, 0.25f, 0);
}

// Round 3
// 675.515 us; speedup vs baseline: 1.6079x; 1.2254x over previous
//
#include <hip/hip_runtime.h>
#include <hip/hip_fp16.h>

#define NU 100000      // users
#define NI 50000       // items
#define NN 150000      // total nodes
#define DIM 128        // embedding dim
#define NH 64          // half2 per row
#define NE 2000000     // directed edges (symmetrized)

// ---------------- CSR build ----------------

__global__ void zero_kernel(int* __restrict__ p, int n) {
    int i = blockIdx.x * blockDim.x + threadIdx.x;
    if (i < n) p[i] = 0;
}

__global__ void hist_kernel(const int* __restrict__ col, int* __restrict__ deg) {
    int e = blockIdx.x * blockDim.x + threadIdx.x;
    if (e < NE) atomicAdd(&deg[col[e]], 1);
}

__global__ void dinv_kernel(const int* __restrict__ deg, float* __restrict__ dinv) {
    int i = blockIdx.x * blockDim.x + threadIdx.x;
    if (i < NN) {
        int d = deg[i];
        dinv[i] = (d > 0) ? 1.0f / sqrtf((float)d) : 0.0f;
    }
}

// wave-level shuffle prefix-scan + one atomicAdd per wave for segment bases
__global__ void alloc_kernel(const int* __restrict__ deg, int* __restrict__ ptr,
                             int* __restrict__ counter) {
    int i = blockIdx.x * blockDim.x + threadIdx.x;
    int lane = threadIdx.x & 63;
    int d = (i < NN) ? deg[i] : 0;
    int incl = d;
    #pragma unroll
    for (int off = 1; off < 64; off <<= 1) {
        int v = __shfl_up(incl, off, 64);
        if (lane >= off) incl += v;
    }
    int total = __shfl(incl, 63, 64);
    int base = 0;
    if (lane == 63) base = atomicAdd(counter, total);
    base = __shfl(base, 63, 64);
    if (i < NN) ptr[i] = base + incl - d;
}

__global__ void fill_kernel(const int* __restrict__ row, const int* __restrict__ col,
                            const int* __restrict__ ptr, int* __restrict__ fill,
                            int* __restrict__ adj) {
    int e = blockIdx.x * blockDim.x + threadIdx.x;
    if (e < NE) {
        int c = col[e];
        int p = atomicAdd(&fill[c], 1);
        adj[ptr[c] + p] = row[e];
    }
}

// ---------------- fp16 conversion of x0 ----------------
// x16 layout: [NN * 64] __half2 (node-major, 256 B per row)
__global__ void convert_kernel(const float* __restrict__ user,
                               const float* __restrict__ item,
                               __half2* __restrict__ x16) {
    int i = blockIdx.x * blockDim.x + threadIdx.x;   // half2 index
    if (i >= NN * NH) return;
    size_t e = (size_t)i * 2;
    const size_t NUsz = (size_t)NU * DIM;
    float2 v = (e < NUsz) ? *(const float2*)(user + e)
                          : *(const float2*)(item + (e - NUsz));
    x16[i] = __floats2half2_rn(v.x, v.y);
}

// ---------------- propagation ----------------
// One wave per target node c; lane L holds dims [2L,2L+1] as one __half2 (4 B).
// Row gather = 64 lanes x 4 B = 256 B coalesced. fp32 accumulate, fp16 store.
__global__ __launch_bounds__(256) void prop_kernel(
    const __half2* __restrict__ xin,
    const float* __restrict__ dinv, const int* __restrict__ ptr,
    const int* __restrict__ deg, const int* __restrict__ adj,
    __half2* __restrict__ xout)
{
    int wid = (blockIdx.x * blockDim.x + threadIdx.x) >> 6;
    if (wid >= NN) return;
    int lane = threadIdx.x & 63;
    int beg = ptr[wid];
    int end = beg + deg[wid];

    float ax0 = 0.f, ay0 = 0.f, ax1 = 0.f, ay1 = 0.f;
    float ax2 = 0.f, ay2 = 0.f, ax3 = 0.f, ay3 = 0.f;
    int j = beg;
    for (; j + 4 <= end; j += 4) {
        int r0 = adj[j], r1 = adj[j + 1], r2 = adj[j + 2], r3 = adj[j + 3];
        float w0 = dinv[r0], w1 = dinv[r1], w2 = dinv[r2], w3 = dinv[r3];
        float2 f0 = __half22float2(xin[(size_t)r0 * NH + lane]);
        float2 f1 = __half22float2(xin[(size_t)r1 * NH + lane]);
        float2 f2 = __half22float2(xin[(size_t)r2 * NH + lane]);
        float2 f3 = __half22float2(xin[(size_t)r3 * NH + lane]);
        ax0 += w0 * f0.x; ay0 += w0 * f0.y;
        ax1 += w1 * f1.x; ay1 += w1 * f1.y;
        ax2 += w2 * f2.x; ay2 += w2 * f2.y;
        ax3 += w3 * f3.x; ay3 += w3 * f3.y;
    }
    for (; j < end; ++j) {
        int r0 = adj[j];
        float w0 = dinv[r0];
        float2 f0 = __half22float2(xin[(size_t)r0 * NH + lane]);
        ax0 += w0 * f0.x; ay0 += w0 * f0.y;
    }
    float dc = dinv[wid];
    float nx = dc * ((ax0 + ax1) + (ax2 + ax3));
    float ny = dc * ((ay0 + ay1) + (ay2 + ay3));
    xout[(size_t)wid * NH + lane] = __floats2half2_rn(nx, ny);
}

// ---------------- final accumulation ----------------
// out = (x0_fp32 + x1 + x2 + x3) * 0.25 ; pure streaming.
__global__ void final_kernel(const float* __restrict__ user,
                             const float* __restrict__ item,
                             const __half2* __restrict__ x1,
                             const __half2* __restrict__ x2,
                             const __half2* __restrict__ x3,
                             float2* __restrict__ out) {
    int i = blockIdx.x * blockDim.x + threadIdx.x;   // half2 / float2 pair index
    if (i >= NN * NH) return;
    size_t e = (size_t)i * 2;
    const size_t NUsz = (size_t)NU * DIM;
    float2 v0 = (e < NUsz) ? *(const float2*)(user + e)
                           : *(const float2*)(item + (e - NUsz));
    float2 f1 = __half22float2(x1[i]);
    float2 f2 = __half22float2(x2[i]);
    float2 f3 = __half22float2(x3[i]);
    float2 o;
    o.x = (v0.x + f1.x + f2.x + f3.x) * 0.25f;
    o.y = (v0.y + f1.y + f2.y + f3.y) * 0.25f;
    out[i] = o;
}

// ---------------- launch ----------------

extern "C" void kernel_launch(void* const* d_in, const int* in_sizes, int n_in,
                              void* d_out, int out_size, void* d_ws, size_t ws_size,
                              hipStream_t stream) {
    const int* edge = (const int*)d_in[0];      // [2, NE] int32
    const int* row = edge;                      // sources
    const int* col = edge + NE;                 // targets
    const float* user = (const float*)d_in[1];  // [NU, DIM]
    const float* item = (const float*)d_in[2];  // [NI, DIM]
    float* out = (float*)d_out;                 // [NN, DIM]

    char* ws = (char*)d_ws;
    size_t off = 0;
    auto alloc = [&](size_t bytes) -> void* {
        void* p = ws + off;
        off = (off + bytes + 255) & ~(size_t)255;
        return p;
    };
    __half2* x0 = (__half2*)alloc(sizeof(__half2) * (size_t)NN * NH);  // 38.4 MB
    __half2* x1 = (__half2*)alloc(sizeof(__half2) * (size_t)NN * NH);
    __half2* x2 = (__half2*)alloc(sizeof(__half2) * (size_t)NN * NH);
    __half2* x3 = (__half2*)alloc(sizeof(__half2) * (size_t)NN * NH);
    float* dinv = (float*)alloc(sizeof(float) * NN);
    int*   deg  = (int*)  alloc(sizeof(int) * (2 * NN + 1));   // deg + fill + counter
    int*   fill = deg + NN;
    int*   cntr = deg + 2 * NN;
    int*   ptr  = (int*)  alloc(sizeof(int) * NN);
    int*   adj  = (int*)  alloc(sizeof(int) * NE);             // 8 MB

    zero_kernel<<<(2 * NN + 1 + 255) / 256, 256, 0, stream>>>(deg, 2 * NN + 1);
    hist_kernel<<<(NE + 255) / 256, 256, 0, stream>>>(col, deg);
    dinv_kernel<<<(NN + 255) / 256, 256, 0, stream>>>(deg, dinv);
    alloc_kernel<<<(NN + 255) / 256, 256, 0, stream>>>(deg, ptr, cntr);
    fill_kernel<<<(NE + 255) / 256, 256, 0, stream>>>(row, col, ptr, fill, adj);

    int nh_blocks = (NN * NH + 255) / 256;
    convert_kernel<<<nh_blocks, 256, 0, stream>>>(user, item, x0);

    int blocks = (NN + 3) / 4;  // 4 waves (nodes) per 256-thread block
    prop_kernel<<<blocks, 256, 0, stream>>>(x0, dinv, ptr, deg, adj, x1);
    prop_kernel<<<blocks, 256, 0, stream>>>(x1, dinv, ptr, deg, adj, x2);
    prop_kernel<<<blocks, 256, 0, stream>>>(x2, dinv, ptr, deg, adj, x3);

    final_kernel<<<nh_blocks, 256, 0, stream>>>(user, item, x1, x2, x3, (float2*)out);
}